// Round 6
// baseline (326.963 us; speedup 1.0000x reference)
//
#include <hip/hip_runtime.h>
#include <hip/hip_bf16.h>

// Masked MSE loss:
//   cls   = (int)labels[i,0] in {0,1,2,3};  ncols = 1 + 3*cls  (COUNTS=[1,4,7,10])
//   loss  = sum_i sum_{j<ncols_i} (outputs[i,j]-labels[i,j])^2 / N
//
// Round-5 counters: VALUBusy 2.8%, HBM 17% -> limiter is the uncoalesced
// 80-B-stride load pattern (each float4 instr touches ~40 cache lines).
// This version stages tiles through LDS with perfectly unit-stride global
// float4 loads, then reads pairs from LDS (stride-80B ds_read_b128, which
// tiles the 32 banks since gcd(5,8)=1).

__global__ __launch_bounds__(256) void masked_mse_kernel(
    const float* __restrict__ outputs,
    const float* __restrict__ labels,
    float* __restrict__ out,
    int npairs,          // n/2
    int n,               // total rows
    float inv_n) {

    constexpr int TP = 256;        // pairs per tile (1 per thread)
    constexpr int F4 = TP * 5;     // float4s per array per tile = 1280
    __shared__ float4 so[F4];      // 20480 B
    __shared__ float4 sl[F4];      // 20480 B   (40 KB total -> 4 blocks/CU)

    const int tid = threadIdx.x;
    float acc = 0.0f;

    const int ntiles = (npairs + TP - 1) / TP;
    for (int tile = blockIdx.x; tile < ntiles; tile += gridDim.x) {
        const int pbase  = tile * TP;
        const int pleft  = min(TP, npairs - pbase);
        const int f4left = pleft * 5;
        const float4* og = reinterpret_cast<const float4*>(outputs) + (size_t)pbase * 5;
        const float4* lg = reinterpret_cast<const float4*>(labels)  + (size_t)pbase * 5;

        // Stage: block-contiguous float4 loads (lane-adjacent 16 B).
        #pragma unroll
        for (int v = 0; v < 5; ++v) {
            int m = v * TP + tid;
            if (m < f4left) {
                so[m] = og[m];
                sl[m] = lg[m];
            }
        }
        __syncthreads();

        if (tid < pleft) {
            float o[20], l[20];
            #pragma unroll
            for (int v = 0; v < 5; ++v) {
                float4 a = so[tid * 5 + v];
                float4 b = sl[tid * 5 + v];
                o[4*v+0] = a.x; o[4*v+1] = a.y; o[4*v+2] = a.z; o[4*v+3] = a.w;
                l[4*v+0] = b.x; l[4*v+1] = b.y; l[4*v+2] = b.z; l[4*v+3] = b.w;
            }

            // Row 0 of the pair: class id in l[0]
            int nc0 = 1 + 3 * (int)l[0];
            #pragma unroll
            for (int j = 0; j < 10; ++j) {
                float d = o[j] - l[j];
                acc += (j < nc0) ? d * d : 0.0f;
            }
            // Row 1 of the pair: class id in l[10]
            int nc1 = 1 + 3 * (int)l[10];
            #pragma unroll
            for (int j = 0; j < 10; ++j) {
                float d = o[10 + j] - l[10 + j];
                acc += (j < nc1) ? d * d : 0.0f;
            }
        }
        __syncthreads();   // protect LDS overwrite next iteration
    }

    // Tail row if n is odd (not the case for N=4e6, but be safe).
    if ((n & 1) && blockIdx.x == 0 && threadIdx.x == 0) {
        int row = n - 1;
        const float* orow = outputs + (size_t)row * 10;
        const float* lrow = labels  + (size_t)row * 10;
        int nc = 1 + 3 * (int)lrow[0];
        for (int j = 0; j < nc; ++j) {
            float d = orow[j] - lrow[j];
            acc += d * d;
        }
    }

    // Wave-64 reduction
    #pragma unroll
    for (int off = 32; off > 0; off >>= 1)
        acc += __shfl_down(acc, off, 64);

    __shared__ float red[4];  // 256 threads -> 4 waves
    const int lane = threadIdx.x & 63;
    const int wid  = threadIdx.x >> 6;
    if (lane == 0) red[wid] = acc;
    __syncthreads();

    if (wid == 0) {
        float v = (lane < 4) ? red[lane] : 0.0f;
        #pragma unroll
        for (int off = 2; off > 0; off >>= 1)
            v += __shfl_down(v, off, 64);
        if (lane == 0)
            atomicAdd(out, v * inv_n);
    }
}

extern "C" void kernel_launch(void* const* d_in, const int* in_sizes, int n_in,
                              void* d_out, int out_size, void* d_ws, size_t ws_size,
                              hipStream_t stream) {
    const float* outputs = (const float*)d_in[0];
    const float* labels  = (const float*)d_in[1];
    float* out = (float*)d_out;

    const int n = in_sizes[0] / 10;   // rows
    const int npairs = n / 2;
    const float inv_n = 1.0f / (float)n;

    // d_out is poisoned to 0xAA before every replay; zero it (capture-safe).
    (void)hipMemsetAsync(out, 0, sizeof(float), stream);

    const int block = 256;
    const int ntiles = (npairs + 255) / 256;
    int grid = ntiles < 1024 ? ntiles : 1024;   // 4 blocks/CU (LDS-limited)

    masked_mse_kernel<<<grid, block, 0, stream>>>(outputs, labels, out,
                                                  npairs, n, inv_n);
}

// Round 8
// 326.901 us; speedup vs baseline: 1.0002x; 1.0002x over previous
//
#include <hip/hip_runtime.h>
#include <hip/hip_bf16.h>

// Masked MSE loss:
//   cls   = (int)labels[i,0] in {0,1,2,3};  ncols = 1 + 3*cls  (COUNTS=[1,4,7,10])
//   loss  = sum_i sum_{j<ncols_i} (outputs[i,j]-labels[i,j])^2 / N
//
// Rounds 2-6 falsified VALU-bound and coalescing theories (all ~120us,
// VALUBusy 4%, HBM 17%). Remaining theory: per-wave MLP starvation --
// VGPR_Count=28 proves the compiler serialized loads. This version forces
// 20 independent float4 loads in flight per thread (4 rows = 160 B
// contiguous per array), one-shot grid (no reuse loop), no LDS staging.

__global__ __launch_bounds__(512) void masked_mse_kernel(
    const float* __restrict__ outputs,
    const float* __restrict__ labels,
    float* __restrict__ out,
    int ngroups,         // ceil(n/4): 4-row groups
    int n,               // total rows
    float inv_n) {

    const int t = blockIdx.x * blockDim.x + threadIdx.x;
    float acc = 0.0f;

    if (t < ngroups) {
        const int r0 = t * 4;
        if (r0 + 4 <= n) {
            // 4 full rows = 40 floats = 10 float4 per array, contiguous.
            const float4* ob = reinterpret_cast<const float4*>(outputs) + (size_t)t * 10;
            const float4* lb = reinterpret_cast<const float4*>(labels)  + (size_t)t * 10;

            // Issue all 20 loads before any use: ~20 KB in flight per wave.
            float4 O[10], L[10];
            #pragma unroll
            for (int i = 0; i < 10; ++i) O[i] = ob[i];
            #pragma unroll
            for (int i = 0; i < 10; ++i) L[i] = lb[i];

            float o[40], l[40];
            #pragma unroll
            for (int i = 0; i < 10; ++i) {
                o[4*i+0] = O[i].x; o[4*i+1] = O[i].y; o[4*i+2] = O[i].z; o[4*i+3] = O[i].w;
                l[4*i+0] = L[i].x; l[4*i+1] = L[i].y; l[4*i+2] = L[i].z; l[4*i+3] = L[i].w;
            }

            #pragma unroll
            for (int r = 0; r < 4; ++r) {
                const int nc = 1 + 3 * (int)l[r*10];
                #pragma unroll
                for (int j = 0; j < 10; ++j) {
                    float d = o[r*10 + j] - l[r*10 + j];
                    acc += (j < nc) ? d * d : 0.0f;
                }
            }
        } else {
            // Ragged tail (n not multiple of 4): scalar per-row path.
            for (int r = r0; r < n; ++r) {
                const float* orow = outputs + (size_t)r * 10;
                const float* lrow = labels  + (size_t)r * 10;
                int nc = 1 + 3 * (int)lrow[0];
                for (int j = 0; j < nc; ++j) {
                    float d = orow[j] - lrow[j];
                    acc += d * d;
                }
            }
        }
    }

    // Wave-64 reduction
    #pragma unroll
    for (int off = 32; off > 0; off >>= 1)
        acc += __shfl_down(acc, off, 64);

    __shared__ float red[8];  // 512 threads -> 8 waves
    const int lane = threadIdx.x & 63;
    const int wid  = threadIdx.x >> 6;
    if (lane == 0) red[wid] = acc;
    __syncthreads();

    if (wid == 0) {
        float v = (lane < 8) ? red[lane] : 0.0f;
        #pragma unroll
        for (int off = 4; off > 0; off >>= 1)
            v += __shfl_down(v, off, 64);
        if (lane == 0)
            atomicAdd(out, v * inv_n);
    }
}

extern "C" void kernel_launch(void* const* d_in, const int* in_sizes, int n_in,
                              void* d_out, int out_size, void* d_ws, size_t ws_size,
                              hipStream_t stream) {
    const float* outputs = (const float*)d_in[0];
    const float* labels  = (const float*)d_in[1];
    float* out = (float*)d_out;

    const int n = in_sizes[0] / 10;       // rows (4,000,000)
    const int ngroups = (n + 3) / 4;      // 4-row groups (1,000,000)
    const float inv_n = 1.0f / (float)n;

    // d_out is poisoned to 0xAA before every replay; zero it (capture-safe).
    (void)hipMemsetAsync(out, 0, sizeof(float), stream);

    const int block = 512;
    const int grid = (ngroups + block - 1) / block;   // exact cover, one shot

    masked_mse_kernel<<<grid, block, 0, stream>>>(outputs, labels, out,
                                                  ngroups, n, inv_n);
}